// Round 19
// baseline (57.771 us; speedup 1.0000x reference)
//
#include <hip/hip_runtime.h>
#include <math.h>

#define L_SEQ 2048
#define H_CH  512
#define N_ST  64
#define BLK   1024  // threads per fftconv block (2 blocks/CU = 32 waves/CU)

__device__ __forceinline__ float frcp(float x) { return __builtin_amdgcn_rcpf(x); }
// float2-granular LDS pad for FFT buffers
#define A2(i) ((i) + ((i) >> 4))

// Wave-local sync: compiler fence only. Valid when both the producers of this
// wave's next reads and the consumers of its writes are THIS wave (LDS ops of
// one wave complete in order; aliasing keeps compiler order).
#define WSYNC() __builtin_amdgcn_wave_barrier()

// ---------------------------------------------------------------------------
// One radix-2^2 quad butterfly: two DIF stages fused in registers.
// ---------------------------------------------------------------------------
__device__ __forceinline__ void quad_bfly(float2* __restrict__ buf,
                                          const float2 w1, const float2 w2,
                                          float S, int e00, int e01, int e10, int e11)
{
    const float2 u0 = buf[e00], u1 = buf[e01];
    const float2 v0 = buf[e10], v1 = buf[e11];
    const float w1y = S * w1.y, w2y = S * w2.y;
    const float2 A = make_float2(u0.x + v0.x, u0.y + v0.y);
    const float2 C = make_float2(u1.x + v1.x, u1.y + v1.y);
    float dx = u0.x - v0.x, dy = u0.y - v0.y;
    const float2 B  = make_float2(dx * w1.x - dy * w1y, dx * w1y + dy * w1.x);
    dx = u1.x - v1.x;  dy = u1.y - v1.y;
    const float2 Dc = make_float2(dx * w1.x - dy * w1y, dx * w1y + dy * w1.x);
    const float2 D  = make_float2(-S * Dc.y, S * Dc.x);          // * iS
    buf[e00] = make_float2(A.x + C.x, A.y + C.y);
    dx = A.x - C.x;  dy = A.y - C.y;
    buf[e01] = make_float2(dx * w2.x - dy * w2y, dx * w2y + dy * w2.x);
    buf[e10] = make_float2(B.x + D.x, B.y + D.y);
    dx = B.x - D.x;  dy = B.y - D.y;
    buf[e11] = make_float2(dx * w2.x - dy * w2y, dx * w2y + dy * w2.x);
}

// ---------------------------------------------------------------------------
// Radix-2^2 DIF FFT in LDS: stages ST0..STEND-1. Natural in, bit-reversed out.
// tw[A2(k)] = e^{+2pi i k/2048}. ssign=-1 fwd, +1 inv (unnormalized).
// Inter-pair sync demoted to wave-local once block size N>>st <= 256 (wave
// owns its 256-span for BOTH the just-written and next-read pair) AND the
// next consumer is another in-function stage pair (not a cross-reading phase).
// ---------------------------------------------------------------------------
template<int LOGN, int ST0, int STEND>
__device__ __forceinline__ void fft4_lds(float2* buf, const float2* tw,
                                         int tid, float ssign)
{
    constexpr int N  = 1 << LOGN;
    constexpr int SH = 11 - LOGN;
    int st = ST0;
    if constexpr (((STEND - ST0) & 1) != 0) {
        const int H = (N >> 1) >> ST0;
        for (int b = tid; b < N / 2; b += BLK) {
            const int j  = b & (H - 1);
            const int i0 = ((b >> (LOGN - 1 - ST0)) << (LOGN - ST0)) + j;
            const int i1 = i0 + H;
            const float2 uu = buf[A2(i0)];
            const float2 vv = buf[A2(i1)];
            const float2 w  = tw[A2((j << ST0) << SH)];
            const float  wy = ssign * w.y;
            buf[A2(i0)] = make_float2(uu.x + vv.x, uu.y + vv.y);
            const float d0 = uu.x - vv.x, d1 = uu.y - vv.y;
            buf[A2(i1)] = make_float2(d0 * w.x - d1 * wy, d0 * wy + d1 * w.x);
        }
        __syncthreads();
        st = ST0 + 1;
    }
    for (; st < STEND; st += 2) {
        const int H  = (N >> 1) >> st;
        const int HQ = H >> 1;
        for (int q = tid; q < N / 4; q += BLK) {
            const int j   = q & (HQ - 1);
            const int blk = q >> (LOGN - 2 - st);
            const int i0  = (blk << (LOGN - st)) + j;
            quad_bfly(buf,
                      tw[A2((j << st) << SH)],
                      tw[A2((j << (st + 1)) << SH)],
                      ssign,
                      A2(i0), A2(i0 + HQ), A2(i0 + H), A2(i0 + H + HQ));
        }
        if ((st + 2 < STEND) && ((N >> st) <= 256)) { WSYNC(); }
        else                                        { __syncthreads(); }
    }
}

// Dual: K- and U-FFTs under shared syncs, split across thread halves.
template<int LOGN, int ST0, int STEND>
__device__ __forceinline__ void fft4_lds_dual(float2* bK, float2* bU,
                                              const float2* tw, int tid, float ssign)
{
    constexpr int N  = 1 << LOGN;
    constexpr int SH = 11 - LOGN;
    constexpr int NH = BLK / 2;            // 512
    static_assert(BLK == N / 2, "dual split needs BLK == N/2");
    float2* bb = (tid < NH) ? bK : bU;     // wave-uniform
    const int q = tid & (NH - 1);
    int st = ST0;
    if constexpr (((STEND - ST0) & 1) != 0) {
        const int H = (N >> 1) >> ST0;
#pragma unroll
        for (int bq = 0; bq < 2; ++bq) {
            const int b  = q + bq * NH;
            const int j  = b & (H - 1);
            const int i0 = ((b >> (LOGN - 1 - ST0)) << (LOGN - ST0)) + j;
            const int i1 = i0 + H;
            const float2 uu = bb[A2(i0)];
            const float2 vv = bb[A2(i1)];
            const float2 w  = tw[A2((j << ST0) << SH)];
            const float  wy = ssign * w.y;
            bb[A2(i0)] = make_float2(uu.x + vv.x, uu.y + vv.y);
            const float d0 = uu.x - vv.x, d1 = uu.y - vv.y;
            bb[A2(i1)] = make_float2(d0 * w.x - d1 * wy, d0 * wy + d1 * w.x);
        }
        __syncthreads();
        st = ST0 + 1;
    }
    for (; st < STEND; st += 2) {
        const int H  = (N >> 1) >> st;
        const int HQ = H >> 1;
        const int j   = q & (HQ - 1);
        const int blk = q >> (LOGN - 2 - st);
        const int i0  = (blk << (LOGN - st)) + j;
        quad_bfly(bb,
                  tw[A2((j << st) << SH)],
                  tw[A2((j << (st + 1)) << SH)],
                  ssign,
                  A2(i0), A2(i0 + HQ), A2(i0 + H), A2(i0 + H + HQ));
        if ((st + 2 < STEND) && ((N >> st) <= 256)) { WSYNC(); }
        else                                        { __syncthreads(); }
    }
}

// ---------------------------------------------------------------------------
// Kernel 0: precompute per-(h,n) Cauchy weights into global scratch.
// ---------------------------------------------------------------------------
__global__ __launch_bounds__(256)
void s4_prep(const float* __restrict__ lam_r_g, const float* __restrict__ lam_i_g,
             const float* __restrict__ p_r_g,  const float* __restrict__ p_i_g,
             const float* __restrict__ b_r_g,  const float* __restrict__ b_i_g,
             const float* __restrict__ c_g,
             float4* __restrict__ Wa, float4* __restrict__ Wb, float* __restrict__ Wc)
{
    const int g = blockIdx.x * 256 + threadIdx.x;      // [0, 512*64)
    const float lr = fminf(lam_r_g[g], -0.0001f);
    const float li = lam_i_g[g];
    const float pr = p_r_g[g], pi = p_i_g[g];
    const float br = b_r_g[g], bi = b_i_g[g];
    const float c0 = c_g[2 * g], c1 = c_g[2 * g + 1];
    Wa[g] = make_float4(lr, li, c0 * br + c1 * bi, c0 * bi - c1 * br);
    Wb[g] = make_float4(c0 * pr + c1 * pi, c0 * pi - c1 * pr,
                        pr * br + pi * bi, pr * bi - pi * br);
    Wc[g] = pr * pr + pi * pi;
}

// ---------------------------------------------------------------------------
// Kernel 1: FUSED cauchy + spectral convolution, one block (1024 thr) per h.
// ---------------------------------------------------------------------------
__global__ __launch_bounds__(BLK, 8)
void s4_fftconv(const float4* __restrict__ Wa, const float4* __restrict__ Wb,
                const float* __restrict__ Wc, const float* __restrict__ log_step_g,
                const float* __restrict__ u, float* __restrict__ Y)
{
    __shared__ float2 bufK[2175];   // A2(2047)=2174
    __shared__ float2 bufU[2175];   // first acts as roots scratch (natural idx)
    __shared__ float2 tw[1087];     // A2(1023)=1086
    const int h   = blockIdx.x;
    const int tid = threadIdx.x;    // [0, 1024)
    float2* __restrict__ rbuf = bufU;          // roots[0..2047], natural index

    // u prefetch first: HBM latency hides under the cauchy FMA phase
    const float uv0 = u[tid * H_CH + h];
    const float uv1 = u[(tid + 1024) * H_CH + h];

    {
        float sv, cv;
        sincosf((float)tid * (6.2831853071795864769f / 2048.0f), &sv, &cv);
        tw[A2(tid)] = make_float2(cv, sv);
    }

    // ---- phase 0: cauchy into LDS (2 points/thread: l = tid, tid+1024) ----
    const float step = expf(log_step_g[h]);
    const float ts   = 2.0f / step;
    const float4* __restrict__ wa = Wa + h * N_ST;
    const float4* __restrict__ wb = Wb + h * N_ST;
    const float*  __restrict__ wc = Wc + h * N_ST;

    {
        float grq[2], giq[2], c2rq[2], c2iq[2];
#pragma unroll
        for (int q = 0; q < 2; ++q) {
            const int l = tid + q * BLK;
            float wi, wr;
            sincosf(-6.2831853071795864769f * ((float)l * (1.0f / (float)L_SEQ)),
                    &wi, &wr);
            const float dr = 1.0f + wr, di = wi;
            const float dv = frcp(dr * dr + di * di);
            const float nr = 1.0f - wr, ni = -wi;
            grq[q]  = ts * (nr * dr + ni * di) * dv;
            giq[q]  = ts * (ni * dr - nr * di) * dv;
            c2rq[q] = 2.0f * dr * dv;
            c2iq[q] = -2.0f * di * dv;
        }
        float s00r[2] = {0,0}, s00i[2] = {0,0};
        float s01r[2] = {0,0}, s01i[2] = {0,0};
        float s10r[2] = {0,0}, s10i[2] = {0,0};
        float s11r[2] = {0,0}, s11i[2] = {0,0};
#pragma unroll 4
        for (int n = 0; n < N_ST; ++n) {
            const float4 A = wa[n];
            const float4 B = wb[n];
            const float w11 = wc[n];
#pragma unroll
            for (int q = 0; q < 2; ++q) {
                const float ddr = grq[q] - A.x;
                const float ddi = giq[q] - A.y;
                const float rinv = frcp(fmaf(ddr, ddr, ddi * ddi));
                const float rr = ddr * rinv;
                const float ri = -ddi * rinv;
                s00r[q] = fmaf(A.z, rr, fmaf(-A.w, ri, s00r[q]));
                s00i[q] = fmaf(A.z, ri, fmaf( A.w, rr, s00i[q]));
                s01r[q] = fmaf(B.x, rr, fmaf(-B.y, ri, s01r[q]));
                s01i[q] = fmaf(B.x, ri, fmaf( B.y, rr, s01i[q]));
                s10r[q] = fmaf(B.z, rr, fmaf(-B.w, ri, s10r[q]));
                s10i[q] = fmaf(B.z, ri, fmaf( B.w, rr, s10i[q]));
                s11r[q] = fmaf(w11, rr, s11r[q]);
                s11i[q] = fmaf(w11, ri, s11i[q]);
            }
        }
#pragma unroll
        for (int q = 0; q < 2; ++q) {
            const float qdr = 1.0f + s11r[q], qdi = s11i[q];
            const float qinv = frcp(qdr * qdr + qdi * qdi);
            const float pnr = s01r[q] * s10r[q] - s01i[q] * s10i[q];
            const float pni = s01r[q] * s10i[q] + s01i[q] * s10r[q];
            const float qr = (pnr * qdr + pni * qdi) * qinv;
            const float qi = (pni * qdr - pnr * qdi) * qinv;
            const float rr0 = s00r[q] - qr, ri0 = s00i[q] - qi;
            rbuf[tid + q * BLK] =
                make_float2(c2rq[q] * rr0 - c2iq[q] * ri0,
                            c2rq[q] * ri0 + c2iq[q] * rr0);
        }
    }

    __syncthreads();   // roots + tw visible

    // ---- phase 1: half-size irfft pack + 1024-pt inverse FFT (stages 0..8) ----
    {
        const int k = tid;              // [0,1024)
        float zr, zi;
        if (k == 0) {
            const float X0 = rbuf[0].x, XM = rbuf[1024].x;
            zr = X0 + XM;  zi = X0 - XM;
        } else {
            const float2 a  = rbuf[k],        b2 = rbuf[2048 - k];
            const float2 a2 = rbuf[1024 - k], b3 = rbuf[1024 + k];
            const float xkr = 0.5f * (a.x + b2.x),  xki = 0.5f * (a.y - b2.y);
            const float xmr = 0.5f * (a2.x + b3.x), xmi = -0.5f * (a2.y - b3.y);
            const float er = xkr + xmr, ei = xki + xmi;
            const float o_r = xkr - xmr, o_i = xki - xmi;
            const float2 w = tw[A2(k)];      // (cos, sin) of +2pi k/2048
            zr = er - fmaf(w.x, o_i,  w.y * o_r);
            zi = ei + fmaf(w.x, o_r, -w.y * o_i);
        }
        bufK[A2(k)] = make_float2(zr, zi);
    }
    __syncthreads();
    fft4_lds<10, 0, 9>(bufK, tw, tid, 1.0f);   // stage 9 fused into pack below

    // ---- phase 2+3: pack K (kern halves via reg-combined last stage) AND U,
    //      fused stage-0 (zero-pad), dual fwd FFT stages 1..9 ----
    float2 vk;
    {
        const int n0 = tid >> 1;                  // [0,512)
        const int e  = __brev(n0) >> 22;          // brev10(n0), even
        const float2 x0 = bufK[A2(e)];
        const float2 x1 = bufK[A2(e + 1)];
        // fused last stage of the 1024-pt iFFT (W=1): z[n0]=x0+x1, z[n0+512]=x0-x1
        const float zar = x0.x + x1.x, zai = x0.y + x1.y;
        const float zbr = x0.x - x1.x, zbi = x0.y - x1.y;
        const float k0v = ((tid & 1) ? zai : zar) * (1.0f / 2048.0f);
        const float k1v = ((tid & 1) ? zbi : zbr) * (1.0f / 2048.0f);
        vk = make_float2(k0v, k1v);
    }
    __syncthreads();
    {
        const int t = tid;
        const float2 w = tw[A2(t)];
        bufK[A2(t)] = vk;
        bufK[A2(t + 1024)] = make_float2(fmaf(vk.x, w.x,  vk.y * w.y),
                                         fmaf(vk.y, w.x, -vk.x * w.y));
        const float2 vu = make_float2(uv0, uv1);
        bufU[A2(t)] = vu;
        bufU[A2(t + 1024)] = make_float2(fmaf(vu.x, w.x,  vu.y * w.y),
                                         fmaf(vu.y, w.x, -vu.x * w.y));
    }
    __syncthreads();
    fft4_lds_dual<11, 1, 10>(bufK, bufU, tw, tid, -1.0f);  // stage 10 fused below

    // ---- phase 4: reconstruct bins from pre-stage-10 pairs, Hermitian unpack,
    //      pointwise product, write with fused inverse stage-0 ----
    float2 Rsum, Rdif;
    {
        const int e    = __brev(tid) >> 21;          // brev11(tid), even
        const int sMir = (1024 - tid) & 1023;
        const int ep   = __brev(sMir) >> 21;         // even
        const float2 kx0 = bufK[A2(e)],  kx1 = bufK[A2(e + 1)];
        const float2 ky0 = bufK[A2(ep)], ky1 = bufK[A2(ep + 1)];
        const float2 ux0 = bufU[A2(e)],  ux1 = bufU[A2(e + 1)];
        const float2 uy0 = bufU[A2(ep)], uy1 = bufU[A2(ep + 1)];
        // fused fwd stage 10 (W=1): bin m = x0+x1, bin m+1024 = x0-x1
        const float2 ZkM  = make_float2(kx0.x + kx1.x, kx0.y + kx1.y);  // tid
        const float2 ZkM1 = make_float2(kx0.x - kx1.x, kx0.y - kx1.y);  // tid+1024
        const float2 ZkS  = make_float2(ky0.x + ky1.x, ky0.y + ky1.y);  // sMir
        const float2 ZkS1 = make_float2(ky0.x - ky1.x, ky0.y - ky1.y);  // sMir+1024
        const float2 ZuM  = make_float2(ux0.x + ux1.x, ux0.y + ux1.y);
        const float2 ZuM1 = make_float2(ux0.x - ux1.x, ux0.y - ux1.y);
        const float2 ZuS  = make_float2(uy0.x + uy1.x, uy0.y + uy1.y);
        const float2 ZuS1 = make_float2(uy0.x - uy1.x, uy0.y - uy1.y);
        const bool self = (tid == 0);   // bins 0 and 1024 are self-mirrored

        float2 R[2];
#pragma unroll
        for (int q = 0; q < 2; ++q) {
            const float2 Zk  = q ? ZkM1 : ZkM;
            const float2 Zu  = q ? ZuM1 : ZuM;
            const float2 Zkp = self ? Zk : (q ? ZkS : ZkS1);
            const float2 Zup = self ? Zu : (q ? ZuS : ZuS1);
            const float F0r = 0.5f * (Zk.x + Zkp.x), F0i = 0.5f * (Zk.y - Zkp.y);
            const float F1r = 0.5f * (Zk.y + Zkp.y), F1i = 0.5f * (Zkp.x - Zk.x);
            const float U0r = 0.5f * (Zu.x + Zup.x), U0i = 0.5f * (Zu.y - Zup.y);
            const float U1r = 0.5f * (Zu.y + Zup.y), U1i = 0.5f * (Zup.x - Zu.x);
            const float Pr = F0r * U0r - F0i * U0i;
            const float Pi = F0r * U0i + F0i * U0r;
            const float Qr = F0r * U1r - F0i * U1i + F1r * U0r - F1i * U0i;
            const float Qi = F0r * U1i + F0i * U1r + F1r * U0i + F1i * U0r;
            R[q] = make_float2(Pr - Qi, Pi + Qr);      // R = P + iQ
        }
        Rsum = make_float2(R[0].x + R[1].x, R[0].y + R[1].y);
        Rdif = make_float2(R[0].x - R[1].x, R[0].y - R[1].y);
    }
    __syncthreads();   // all reads of bufK/bufU done before overwrite
    {
        // fused inverse stage 0 (bins tid, tid+1024; j = tid, ssign = +1)
        const float2 w = tw[A2(tid)];
        bufK[A2(tid)]        = Rsum;
        bufK[A2(tid + 1024)] = make_float2(Rdif.x * w.x - Rdif.y * w.y,
                                           Rdif.x * w.y + Rdif.y * w.x);
    }
    __syncthreads();
    fft4_lds<11, 1, 10>(bufK, tw, tid, 1.0f);  // stage 10 fused into epilogue

    // ---- phase 5: epilogue (fused inverse last stage, W=1) ----
    {
        const int e2 = __brev(tid) >> 21;          // brev11(tid), even
        const float2 x0 = bufK[A2(e2)];
        const float2 x1 = bufK[A2(e2 + 1)];
        const float rlx = x0.x + x1.x, rly = x0.y + x1.y;   // r[tid]
        const float rhx = x0.x - x1.x;                       // Re r[tid+1024]
        Y[h * 2048 + tid]        = rlx * (1.0f / 2048.0f);
        Y[h * 2048 + 1024 + tid] = (rhx + rly) * (1.0f / 2048.0f);
    }
}

// ---------------------------------------------------------------------------
// Kernel 2: finish = 64x64 LDS transpose + d*u add.
// ---------------------------------------------------------------------------
__global__ __launch_bounds__(256)
void s4_finish(const float* __restrict__ Y, const float* __restrict__ u,
               const float* __restrict__ dvec, float* __restrict__ out)
{
    __shared__ float tile[64][65];
    const int t0   = blockIdx.x * 64;
    const int h0   = blockIdx.y * 64;
    const int lane = threadIdx.x & 63;
    const int rowg = threadIdx.x >> 6;         // 0..3

#pragma unroll
    for (int rr = 0; rr < 16; ++rr) {
        const int hr = rowg * 16 + rr;
        tile[hr][lane] = Y[(h0 + hr) * 2048 + t0 + lane];
    }
    __syncthreads();

    const float dh = dvec[h0 + lane];
#pragma unroll
    for (int rr = 0; rr < 16; ++rr) {
        const int tr = rowg * 16 + rr;
        const int t  = t0 + tr;
        out[t * H_CH + h0 + lane] =
            fmaf(dh, u[t * H_CH + h0 + lane], tile[lane][tr]);
    }
}

// ---------------------------------------------------------------------------
extern "C" void kernel_launch(void* const* d_in, const int* in_sizes, int n_in,
                              void* d_out, int out_size, void* d_ws, size_t ws_size,
                              hipStream_t stream)
{
    const float* u        = (const float*)d_in[0];
    const float* lam_r    = (const float*)d_in[1];
    const float* lam_i    = (const float*)d_in[2];
    const float* p_r      = (const float*)d_in[3];
    const float* p_i      = (const float*)d_in[4];
    const float* b_r      = (const float*)d_in[5];
    const float* b_i      = (const float*)d_in[6];
    const float* cmat     = (const float*)d_in[7];
    const float* dvec     = (const float*)d_in[8];
    const float* log_step = (const float*)d_in[9];
    float* out = (float*)d_out;

    char* ws = (char*)d_ws;
    float*  Y     = (float*)(ws + (size_t)8 * 1024 * 1024);   // 4 MB @ 8M
    float4* Wa    = (float4*)(ws + (size_t)12 * 1024 * 1024); // 512 KB
    float4* Wb    = (float4*)(ws + (size_t)12 * 1024 * 1024 + 512 * 1024);
    float*  Wc    = (float*) (ws + (size_t)13 * 1024 * 1024); // 128 KB

    s4_prep<<<dim3(H_CH * N_ST / 256), dim3(256), 0, stream>>>(
        lam_r, lam_i, p_r, p_i, b_r, b_i, cmat, Wa, Wb, Wc);
    s4_fftconv<<<dim3(H_CH), dim3(BLK), 0, stream>>>(
        Wa, Wb, Wc, log_step, u, Y);
    s4_finish<<<dim3(L_SEQ / 64, H_CH / 64), dim3(256), 0, stream>>>(
        Y, u, dvec, out);
}